// Round 4
// baseline (194.320 us; speedup 1.0000x reference)
//
#include <hip/hip_runtime.h>
#include <math.h>

#define NCELLS (64 * 128 * 128)            // 1,048,576
#define BLOCK 256
#define CELLS_PER_BLOCK 256                // 1 cell/thread
#define GRID (NCELLS / CELLS_PER_BLOCK)    // 4096 blocks
#define NACC 6
#define EPSV 1e-10f

// ws layout (zeroed by 32B memset each launch):
// [0..5] float accumulators {m, s_noobj, s_nresp, s_xy, s_wh, s_obj}
// [6]    finished-block counter (uint)

__device__ __forceinline__ float sigmoidf_(float x) {
    return 1.0f / (1.0f + __expf(-x));
}
__device__ __forceinline__ float softplusf_(float x) {
    // logaddexp(0,x) = max(x,0) + log(1 + exp(-|x|))
    return fmaxf(x, 0.0f) + __logf(1.0f + __expf(-fabsf(x)));
}
__device__ __forceinline__ float iou_(float cx, float cy, float cw, float ch,
                                      float tx, float ty, float tw, float th) {
    float plx = cx - 0.5f * cw, ply = cy - 0.5f * ch;
    float prx = cx + 0.5f * cw, pry = cy + 0.5f * ch;
    float tlx = tx - 0.5f * tw, tly = ty - 0.5f * th;
    float trx = tx + 0.5f * tw, try_ = ty + 0.5f * th;
    float wx = fmaxf(fminf(prx, trx) - fmaxf(plx, tlx), 0.0f);
    float wy = fmaxf(fminf(pry, try_) - fmaxf(ply, tly), 0.0f);
    float inter = wx * wy;
    return inter / (cw * ch + tw * th - inter + EPSV);
}

// 15.4 KB LDS, <=64 VGPR target: 8 blocks/CU = 32 waves/CU (full occupancy)
__global__ __launch_bounds__(BLOCK, 8) void yolo_fused_kernel(
        const float4* __restrict__ in4,
        const float4* __restrict__ tg4,
        float* __restrict__ ws,
        float* __restrict__ out) {
    __shared__ float lds_in[CELLS_PER_BLOCK * 10];   // 10 KB
    __shared__ float lds_tg[CELLS_PER_BLOCK * 5];    // 5 KB

    const int t = threadIdx.x;

    // Dense, fully-coalesced staging: 640 + 320 float4 per block.
    {
        float4* li = (float4*)lds_in;
        const float4* __restrict__ gp = in4 + (size_t)blockIdx.x * 640;
        li[t] = gp[t];
        li[256 + t] = gp[256 + t];
        if (t < 128) li[512 + t] = gp[512 + t];
        float4* lt = (float4*)lds_tg;
        const float4* __restrict__ tp = tg4 + (size_t)blockIdx.x * 320;
        lt[t] = tp[t];
        if (t < 64) lt[256 + t] = tp[256 + t];
    }
    __syncthreads();

    float m_cnt = 0.0f, s_noobj = 0.0f, s_nresp = 0.0f;
    float s_xy = 0.0f, s_wh = 0.0f, s_obj = 0.0f;

    {
        const float* f = lds_in + t * 10;  // [logit0, x0,y0,w0,h0, logit1, x1,y1,w1,h1]
        const float* tt = lds_tg + t * 5;  // [conf, tx,ty,tw,th]

        float logit0 = f[0], logit1 = f[5];
        float bce0_0 = softplusf_(logit0);
        float bce0_1 = softplusf_(logit1);

        float tx = tt[1], ty = tt[2], tw = tt[3], th = tt[4];
        bool obj = (tt[0] > 0.0f);

        if (!obj) {
            s_noobj = bce0_0 + bce0_1;
        } else {
            m_cnt = 1.0f;
            float cx0 = sigmoidf_(f[1]), cy0 = sigmoidf_(f[2]);
            float cw0 = sigmoidf_(f[3]), ch0 = sigmoidf_(f[4]);
            float cx1 = sigmoidf_(f[6]), cy1 = sigmoidf_(f[7]);
            float cw1 = sigmoidf_(f[8]), ch1 = sigmoidf_(f[9]);

            float iou0 = iou_(cx0, cy0, cw0, ch0, tx, ty, tw, th);
            float iou1 = iou_(cx1, cy1, cw1, ch1, tx, ty, tw, th);
            bool r1 = (iou1 > iou0);   // argmax first-index tie-break

            float rcx = r1 ? cx1 : cx0, rcy = r1 ? cy1 : cy0;
            float rcw = r1 ? cw1 : cw0, rch = r1 ? ch1 : ch0;
            float dx = rcx - tx, dy = rcy - ty;
            float dw = rcw - tw, dh = rch - th;
            s_xy = dx * dx + dy * dy;
            s_wh = dw * dw + dh * dh;
            s_obj = r1 ? (bce0_1 - logit1) : (bce0_0 - logit0);
            s_nresp = r1 ? bce0_0 : bce0_1;
        }
    }

    // 64-lane butterfly reduce, then cross-wave via LDS
    float vals[NACC] = {m_cnt, s_noobj, s_nresp, s_xy, s_wh, s_obj};
    #pragma unroll
    for (int i = 0; i < NACC; ++i) {
        float v = vals[i];
        #pragma unroll
        for (int off = 32; off > 0; off >>= 1) v += __shfl_down(v, off, 64);
        vals[i] = v;
    }

    __shared__ float sm[4][NACC];
    int wave = t >> 6, lane = t & 63;
    if (lane == 0) {
        #pragma unroll
        for (int i = 0; i < NACC; ++i) sm[wave][i] = vals[i];
    }
    __syncthreads();

    // block partials -> global accumulators (device-scope atomics)
    if (t < NACC) {
        float s = sm[0][t] + sm[1][t] + sm[2][t] + sm[3][t];
        atomicAdd(&ws[t], s);
    }
    __syncthreads();

    __shared__ unsigned is_last;
    if (t == 0) {
        __threadfence();
        unsigned old = atomicAdd((unsigned*)&ws[NACC], 1u);
        is_last = (old == GRID - 1) ? 1u : 0u;
    }
    __syncthreads();

    if (is_last && t == 0) {
        __threadfence();
        float m    = atomicAdd(&ws[0], 0.0f);
        float s_no = atomicAdd(&ws[1], 0.0f);
        float s_nr = atomicAdd(&ws[2], 0.0f);
        float sxy  = atomicAdd(&ws[3], 0.0f);
        float swh  = atomicAdd(&ws[4], 0.0f);
        float sob  = atomicAdd(&ws[5], 0.0f);

        float n_noobj = (float)NCELLS - m;
        float loss_noobj = s_no / (n_noobj * 2.0f) + s_nr / m;  // B=2 -> (B-1)=1
        float loss_xy = sxy / (m * 2.0f);
        float loss_wh = swh / (m * 2.0f);
        float loss_obj = sob / m;
        out[0] = loss_noobj + loss_xy + loss_wh + loss_obj;
        out[1] = loss_noobj;
        out[2] = loss_xy;
        out[3] = loss_wh;
        out[4] = loss_obj;
    }
}

extern "C" void kernel_launch(void* const* d_in, const int* in_sizes, int n_in,
                              void* d_out, int out_size, void* d_ws, size_t ws_size,
                              hipStream_t stream) {
    const float4* in4 = (const float4*)d_in[0];
    const float4* tg4 = (const float4*)d_in[1];
    float* out = (float*)d_out;
    float* ws = (float*)d_ws;

    hipMemsetAsync(ws, 0, 32, stream);
    hipLaunchKernelGGL(yolo_fused_kernel, dim3(GRID), dim3(BLOCK), 0, stream,
                       in4, tg4, ws, out);
}

// Round 5
// 99.085 us; speedup vs baseline: 1.9611x; 1.9611x over previous
//
#include <hip/hip_runtime.h>
#include <math.h>

#define NCELLS (64 * 128 * 128)            // 1,048,576
#define BLOCK 256
#define CELLS_PER_BLOCK 256                // 1 cell/thread
#define GRID (NCELLS / CELLS_PER_BLOCK)    // 4096 blocks
#define NACC 6
#define WS_STRIDE 8
#define EPSV 1e-10f

// ws layout: per-block partial rows, ws[b*8 + 0..5] = {m, s_noobj, s_nresp, s_xy, s_wh, s_obj}
// No accumulators shared across blocks -> no contended atomics, no memset needed.

__device__ __forceinline__ float sigmoidf_(float x) {
    return 1.0f / (1.0f + __expf(-x));
}
__device__ __forceinline__ float softplusf_(float x) {
    // logaddexp(0,x) = max(x,0) + log(1 + exp(-|x|))
    return fmaxf(x, 0.0f) + __logf(1.0f + __expf(-fabsf(x)));
}
__device__ __forceinline__ float iou_(float cx, float cy, float cw, float ch,
                                      float tx, float ty, float tw, float th) {
    float plx = cx - 0.5f * cw, ply = cy - 0.5f * ch;
    float prx = cx + 0.5f * cw, pry = cy + 0.5f * ch;
    float tlx = tx - 0.5f * tw, tly = ty - 0.5f * th;
    float trx = tx + 0.5f * tw, try_ = ty + 0.5f * th;
    float wx = fmaxf(fminf(prx, trx) - fmaxf(plx, tlx), 0.0f);
    float wy = fmaxf(fminf(pry, try_) - fmaxf(ply, tly), 0.0f);
    float inter = wx * wy;
    return inter / (cw * ch + tw * th - inter + EPSV);
}

// 15.4 KB LDS; no min-waves clause (round 4: (256,8) forced VGPR=16 -> spill disaster)
__global__ __launch_bounds__(BLOCK) void yolo_main_kernel(
        const float4* __restrict__ in4,
        const float4* __restrict__ tg4,
        float* __restrict__ ws) {
    __shared__ float lds_in[CELLS_PER_BLOCK * 10];   // 10 KB
    __shared__ float lds_tg[CELLS_PER_BLOCK * 5];    // 5 KB

    const int t = threadIdx.x;

    // Dense, fully-coalesced staging: 640 + 320 float4 per block.
    {
        float4* li = (float4*)lds_in;
        const float4* __restrict__ gp = in4 + (size_t)blockIdx.x * 640;
        li[t] = gp[t];
        li[256 + t] = gp[256 + t];
        if (t < 128) li[512 + t] = gp[512 + t];
        float4* lt = (float4*)lds_tg;
        const float4* __restrict__ tp = tg4 + (size_t)blockIdx.x * 320;
        lt[t] = tp[t];
        if (t < 64) lt[256 + t] = tp[256 + t];
    }
    __syncthreads();

    float m_cnt = 0.0f, s_noobj = 0.0f, s_nresp = 0.0f;
    float s_xy = 0.0f, s_wh = 0.0f, s_obj = 0.0f;

    {
        const float* f = lds_in + t * 10;  // [logit0, x0,y0,w0,h0, logit1, x1,y1,w1,h1]
        const float* tt = lds_tg + t * 5;  // [conf, tx,ty,tw,th]

        float logit0 = f[0], logit1 = f[5];
        float bce0_0 = softplusf_(logit0);
        float bce0_1 = softplusf_(logit1);

        float tx = tt[1], ty = tt[2], tw = tt[3], th = tt[4];
        bool obj = (tt[0] > 0.0f);

        if (!obj) {
            s_noobj = bce0_0 + bce0_1;
        } else {
            m_cnt = 1.0f;
            float cx0 = sigmoidf_(f[1]), cy0 = sigmoidf_(f[2]);
            float cw0 = sigmoidf_(f[3]), ch0 = sigmoidf_(f[4]);
            float cx1 = sigmoidf_(f[6]), cy1 = sigmoidf_(f[7]);
            float cw1 = sigmoidf_(f[8]), ch1 = sigmoidf_(f[9]);

            float iou0 = iou_(cx0, cy0, cw0, ch0, tx, ty, tw, th);
            float iou1 = iou_(cx1, cy1, cw1, ch1, tx, ty, tw, th);
            bool r1 = (iou1 > iou0);   // argmax first-index tie-break

            float rcx = r1 ? cx1 : cx0, rcy = r1 ? cy1 : cy0;
            float rcw = r1 ? cw1 : cw0, rch = r1 ? ch1 : ch0;
            float dx = rcx - tx, dy = rcy - ty;
            float dw = rcw - tw, dh = rch - th;
            s_xy = dx * dx + dy * dy;
            s_wh = dw * dw + dh * dh;
            s_obj = r1 ? (bce0_1 - logit1) : (bce0_0 - logit0);
            s_nresp = r1 ? bce0_0 : bce0_1;
        }
    }

    // 64-lane butterfly reduce, then cross-wave via LDS
    float vals[NACC] = {m_cnt, s_noobj, s_nresp, s_xy, s_wh, s_obj};
    #pragma unroll
    for (int i = 0; i < NACC; ++i) {
        float v = vals[i];
        #pragma unroll
        for (int off = 32; off > 0; off >>= 1) v += __shfl_down(v, off, 64);
        vals[i] = v;
    }

    __shared__ float sm[4][NACC];
    int wave = t >> 6, lane = t & 63;
    if (lane == 0) {
        #pragma unroll
        for (int i = 0; i < NACC; ++i) sm[wave][i] = vals[i];
    }
    __syncthreads();

    // Uncontended: each block owns its ws row. Plain stores, no atomics.
    if (t < NACC) {
        ws[(size_t)blockIdx.x * WS_STRIDE + t] = sm[0][t] + sm[1][t] + sm[2][t] + sm[3][t];
    }
}

__global__ __launch_bounds__(1024) void yolo_finalize_kernel(
        const float* __restrict__ ws, float* __restrict__ out) {
    // Reduce 4096 rows x 6 partials (128 KB, L2-hot).
    float acc[NACC] = {0, 0, 0, 0, 0, 0};
    for (int b = threadIdx.x; b < GRID; b += 1024) {
        #pragma unroll
        for (int i = 0; i < NACC; ++i) acc[i] += ws[(size_t)b * WS_STRIDE + i];
    }
    #pragma unroll
    for (int i = 0; i < NACC; ++i) {
        float v = acc[i];
        #pragma unroll
        for (int off = 32; off > 0; off >>= 1) v += __shfl_down(v, off, 64);
        acc[i] = v;
    }
    __shared__ float sm[16][NACC];
    int wave = threadIdx.x >> 6, lane = threadIdx.x & 63;
    if (lane == 0) {
        #pragma unroll
        for (int i = 0; i < NACC; ++i) sm[wave][i] = acc[i];
    }
    __syncthreads();
    if (threadIdx.x == 0) {
        float tot[NACC];
        #pragma unroll
        for (int i = 0; i < NACC; ++i) {
            float s = 0.0f;
            #pragma unroll
            for (int w = 0; w < 16; ++w) s += sm[w][i];
            tot[i] = s;
        }
        float m = tot[0];
        float n_noobj = (float)NCELLS - m;
        float loss_noobj = tot[1] / (n_noobj * 2.0f) + tot[2] / m;  // B=2 -> (B-1)=1
        float loss_xy = tot[3] / (m * 2.0f);
        float loss_wh = tot[4] / (m * 2.0f);
        float loss_obj = tot[5] / m;
        out[0] = loss_noobj + loss_xy + loss_wh + loss_obj;
        out[1] = loss_noobj;
        out[2] = loss_xy;
        out[3] = loss_wh;
        out[4] = loss_obj;
    }
}

extern "C" void kernel_launch(void* const* d_in, const int* in_sizes, int n_in,
                              void* d_out, int out_size, void* d_ws, size_t ws_size,
                              hipStream_t stream) {
    const float4* in4 = (const float4*)d_in[0];
    const float4* tg4 = (const float4*)d_in[1];
    float* out = (float*)d_out;
    float* ws = (float*)d_ws;

    hipLaunchKernelGGL(yolo_main_kernel, dim3(GRID), dim3(BLOCK), 0, stream,
                       in4, tg4, ws);
    hipLaunchKernelGGL(yolo_finalize_kernel, dim3(1), dim3(1024), 0, stream, ws, out);
}